// Round 9
// baseline (202.437 us; speedup 1.0000x reference)
//
#include <hip/hip_runtime.h>

// out[e] = sum_d | h[row[e],d] + g[type[e],d] - h[col[e],d] |
// h: [50000,128] f32, g: [500,128] f32, edge_idx: [2,E] i32, edge_type: [E] i32
//
// R9: R1-R8 converge on a per-random-ACCESS cost model (fixed rows/sec, width-
// independent). Lever: cut random accesses 2->1 per edge by binning edges by
// row>>6 (782 buckets, 8 KB of h8 rows per bucket = L1-resident), then running
// the R6 gather structure over the binned records: h[row] becomes L1-hot,
// h[col] stays random. Pipeline: cvt -> zero -> hist -> scan -> scatter -> main.

#define D 128
typedef float f32x2 __attribute__((ext_vector_type(2)));

// ---- cvt: h,g f32 -> fp8 e4m3 (float4 -> packed dword), contiguous ----
__global__ void __launch_bounds__(256) KB_cvt(
    const float* __restrict__ h_in, unsigned int* __restrict__ h8, int n4_h,
    const float* __restrict__ g_in, unsigned int* __restrict__ g8, int n4_g)
{
    const int total = n4_h + n4_g;
    for (int i = blockIdx.x * 256 + threadIdx.x; i < total; i += gridDim.x * 256) {
        const bool isH = (i < n4_h);
        const int  j   = isH ? i : i - n4_h;
        const float4 v = isH ? reinterpret_cast<const float4*>(h_in)[j]
                             : reinterpret_cast<const float4*>(g_in)[j];
        unsigned int w = 0;
        w = __builtin_amdgcn_cvt_pk_fp8_f32(v.x, v.y, w, false);
        w = __builtin_amdgcn_cvt_pk_fp8_f32(v.z, v.w, w, true);
        (isH ? h8 : g8)[j] = w;
    }
}

// ---- zero hist + cursor ----
__global__ void __launch_bounds__(256) KB_zero(int* __restrict__ p, int n)
{
    const int i = blockIdx.x * 256 + threadIdx.x;
    if (i < n) p[i] = 0;
}

// ---- histogram of row-buckets (LDS-local then one atomic per bucket/block) ----
__global__ void __launch_bounds__(256) KB_hist(
    const int* __restrict__ eidx, int E, int* __restrict__ hist, int nb, int shift)
{
    extern __shared__ int lh[];
    for (int i = threadIdx.x; i < nb; i += 256) lh[i] = 0;
    __syncthreads();
    for (int e = blockIdx.x * 256 + threadIdx.x; e < E; e += gridDim.x * 256)
        atomicAdd(&lh[eidx[e] >> shift], 1);
    __syncthreads();
    for (int i = threadIdx.x; i < nb; i += 256)
        if (lh[i]) atomicAdd(&hist[i], lh[i]);
}

// ---- exclusive scan (single block, nb <= 1024, Hillis-Steele) ----
__global__ void __launch_bounds__(1024) KB_scan(
    const int* __restrict__ hist, int* __restrict__ cursor, int nb)
{
    __shared__ int buf[2][1024];
    const int i = threadIdx.x;
    const int v = (i < nb) ? hist[i] : 0;
    buf[0][i] = v;
    __syncthreads();
    int src = 0;
    for (int off = 1; off < 1024; off <<= 1) {
        int x = buf[src][i];
        if (i >= off) x += buf[src][i - off];
        buf[src ^ 1][i] = x;
        __syncthreads();
        src ^= 1;
    }
    if (i < nb) cursor[i] = buf[src][i] - v;   // exclusive prefix
}

// ---- scatter edges into bucket-ordered record array {r,c,t,e} ----
__global__ void __launch_bounds__(256) KB_scatter(
    const int* __restrict__ eidx, const int* __restrict__ etype, int E,
    int* __restrict__ cursor, int4* __restrict__ rec, int shift)
{
    for (int e = blockIdx.x * 256 + threadIdx.x; e < E; e += gridDim.x * 256) {
        const int r = eidx[e];
        const int c = eidx[E + e];
        const int t = etype[e];
        const int pos = atomicAdd(&cursor[r >> shift], 1);
        rec[pos] = make_int4(r, c, t, e);
    }
}

// ---- main: R6 structure over binned records; h[row] L1-hot, h[col] random ----
__global__ void __launch_bounds__(256, 4) KB_main_sorted(
    const unsigned int* __restrict__ h8,   // 32 dwords (128 B) per node row
    const unsigned int* __restrict__ g8,   // 32 dwords per relation row
    const int4* __restrict__ rec,          // [E] {r,c,t,orig_e}
    float* __restrict__ out,               // [E]
    int E)
{
    const int grp   = (blockIdx.x * 256 + (int)threadIdx.x) >> 3;
    const int sub   = threadIdx.x & 7;
    const int lbase = (threadIdx.x & 63) & ~7;
    const int e0    = grp * 4;
    if (e0 >= E) return;

    // lanes 0..3 load the group's 4 records (64 B contiguous), broadcast
    int4 myrec = make_int4(0, 0, 0, 0);
    if (sub < 4) myrec = rec[min(e0 + sub, E - 1)];

    int r[4], c[4], t[4], eo[4];
    #pragma unroll
    for (int k = 0; k < 4; ++k) {
        r[k]  = __shfl(myrec.x, lbase + k, 64);
        c[k]  = __shfl(myrec.y, lbase + k, 64);
        t[k]  = __shfl(myrec.z, lbase + k, 64);
        eo[k] = __shfl(myrec.w, lbase + k, 64);
    }

    // Issue ALL 12 row-gathers before consuming anything.
    uint4 hr[4], hc[4], gw[4];
    #pragma unroll
    for (int k = 0; k < 4; ++k)
        hc[k] = *reinterpret_cast<const uint4*>(h8 + (size_t)c[k] * 32 + sub * 4);
    #pragma unroll
    for (int k = 0; k < 4; ++k)
        hr[k] = *reinterpret_cast<const uint4*>(h8 + (size_t)r[k] * 32 + sub * 4);
    #pragma unroll
    for (int k = 0; k < 4; ++k)
        gw[k] = *reinterpret_cast<const uint4*>(g8 + (size_t)t[k] * 32 + sub * 4);

    float s0 = 0.f, s1 = 0.f, s2 = 0.f, s3 = 0.f;
    #pragma unroll
    for (int k = 0; k < 4; ++k) {
        const unsigned int ha[4] = {hr[k].x, hr[k].y, hr[k].z, hr[k].w};
        const unsigned int hb[4] = {hc[k].x, hc[k].y, hc[k].z, hc[k].w};
        const unsigned int gg[4] = {gw[k].x, gw[k].y, gw[k].z, gw[k].w};
        float s = 0.f;
        #pragma unroll
        for (int j = 0; j < 4; ++j) {
            const f32x2 a0 = __builtin_amdgcn_cvt_pk_f32_fp8(ha[j], false);
            const f32x2 a1 = __builtin_amdgcn_cvt_pk_f32_fp8(ha[j], true);
            const f32x2 c0 = __builtin_amdgcn_cvt_pk_f32_fp8(hb[j], false);
            const f32x2 c1 = __builtin_amdgcn_cvt_pk_f32_fp8(hb[j], true);
            const f32x2 g0 = __builtin_amdgcn_cvt_pk_f32_fp8(gg[j], false);
            const f32x2 g1 = __builtin_amdgcn_cvt_pk_f32_fp8(gg[j], true);
            s += fabsf(a0.x + g0.x - c0.x) + fabsf(a0.y + g0.y - c0.y)
               + fabsf(a1.x + g1.x - c1.x) + fabsf(a1.y + g1.y - c1.y);
        }
        s += __shfl_xor(s, 4, 8);
        s += __shfl_xor(s, 2, 8);
        s += __shfl_xor(s, 1, 8);
        if (k == 0) s0 = s; else if (k == 1) s1 = s; else if (k == 2) s2 = s; else s3 = s;
    }

    // lane sub<4 stores edge e0+sub to its ORIGINAL position (static selects)
    const float v  = (sub == 0) ? s0    : (sub == 1) ? s1    : (sub == 2) ? s2    : s3;
    const int   eS = (sub == 0) ? eo[0] : (sub == 1) ? eo[1] : (sub == 2) ? eo[2] : eo[3];
    if (sub < 4 && e0 + sub < E)
        __builtin_nontemporal_store(v, out + eS);
}

// ---- fallback: plain f32 path ----
__global__ void __launch_bounds__(256) KB_transe_l1_f32(
    const float* __restrict__ h, const float* __restrict__ g,
    const int* __restrict__ eidx, const int* __restrict__ etype,
    float* __restrict__ out, int E)
{
    const int tid  = blockIdx.x * 256 + threadIdx.x;
    const int edge = tid >> 5;
    const int lane = threadIdx.x & 31;
    if (edge >= E) return;
    const int r = eidx[edge], c = eidx[E + edge], t = etype[edge];
    const int d = lane * 4;
    const float4 hr = *reinterpret_cast<const float4*>(h + (size_t)r * D + d);
    const float4 hc = *reinterpret_cast<const float4*>(h + (size_t)c * D + d);
    const float4 gt = *reinterpret_cast<const float4*>(g + (size_t)t * D + d);
    float s = fabsf(hr.x + gt.x - hc.x) + fabsf(hr.y + gt.y - hc.y)
            + fabsf(hr.z + gt.z - hc.z) + fabsf(hr.w + gt.w - hc.w);
    #pragma unroll
    for (int o = 16; o >= 1; o >>= 1) s += __shfl_xor(s, o, 32);
    if (lane == 0) out[edge] = s;
}

extern "C" void kernel_launch(void* const* d_in, const int* in_sizes, int n_in,
                              void* d_out, int out_size, void* d_ws, size_t ws_size,
                              hipStream_t stream) {
    const float* h     = (const float*)d_in[0];
    const float* g     = (const float*)d_in[1];
    const int*   eidx  = (const int*)d_in[2];
    const int*   etype = (const int*)d_in[3];
    float*       out   = (float*)d_out;

    const int E      = in_sizes[3];
    const int n_h    = in_sizes[0];        // 50000*128
    const int n_g    = in_sizes[1];        // 500*128
    const int nnodes = n_h / D;

    // pick bucket shift so nb <= 1024 (single-block scan)
    int shift = 0;
    while ((((long long)nnodes + (1LL << shift) - 1) >> shift) > 1024) ++shift;
    const int nb = (nnodes + (1 << shift) - 1) >> shift;

    // ws layout: h8 | g8 | hist | cursor | rec
    size_t off = 0;
    unsigned int* h8   = (unsigned int*)d_ws;             off += (size_t)n_h;
    unsigned int* g8   = (unsigned int*)((char*)d_ws + off); off += (size_t)n_g;
    off = (off + 15) & ~(size_t)15;
    int* hist   = (int*)((char*)d_ws + off);              off += (size_t)nb * 4;
    int* cursor = (int*)((char*)d_ws + off);              off += (size_t)nb * 4;
    off = (off + 15) & ~(size_t)15;
    int4* rec   = (int4*)((char*)d_ws + off);             off += (size_t)E * 16;

    const bool ok = (n_h % (4 * D) == 0) && (n_g % (4 * D) == 0) && (ws_size >= off);

    if (ok) {
        const int n4_h = n_h / 4, n4_g = n_g / 4;
        const int cgrid = (n4_h + n4_g + 255) / 256;
        KB_cvt<<<cgrid, 256, 0, stream>>>(h, h8, n4_h, g, g8, n4_g);

        KB_zero<<<(2 * nb + 255) / 256, 256, 0, stream>>>(hist, 2 * nb);
        KB_hist<<<1024, 256, nb * 4, stream>>>(eidx, E, hist, nb, shift);
        KB_scan<<<1, 1024, 0, stream>>>(hist, cursor, nb);
        KB_scatter<<<1024, 256, 0, stream>>>(eidx, etype, E, cursor, rec, shift);

        const int groups = (E + 3) / 4;
        const long long threads = (long long)groups * 8;
        const int grid = (int)((threads + 255) / 256);
        KB_main_sorted<<<grid, 256, 0, stream>>>(h8, g8, rec, out, E);
    } else {
        const long long threads = (long long)E * 32;
        const int grid = (int)((threads + 255) / 256);
        KB_transe_l1_f32<<<grid, 256, 0, stream>>>(h, g, eidx, etype, out, E);
    }
}

// Round 10
// 29.533 us; speedup vs baseline: 6.8545x; 6.8545x over previous
//
#include <hip/hip_runtime.h>
#include <hip/hip_fp16.h>

// out[e] = sum_d | h[row[e],d] + g[type[e],d] - h[col[e],d] |
// h: [50000,128] f32, g: [500,128] f32, edge_idx: [2,E] i32, edge_type: [E] i32
//
// R10 = revert to R6 (best measured: 29.12 us). Unified model from R1-R9:
// gather time = random 64B L2-line-requests / ~104-110 G req/s (CU->TCC
// crossbar cap). fp8 rows (128 B = 2 lines) x 2 rows/edge = 2.4 M requests
// ~= 23 us main; + 32 MB cvt streaming ~= 6 us. MLP, g-in-LDS, L2 residency,
// row-width halving, and sort-binning all failed to beat this; floor ~= 29 us.

#define D 128
typedef float f32x2 __attribute__((ext_vector_type(2)));

// ---- conversion: h f32->fp8 e4m3, g f32->fp8 (float4 -> packed dword) ----
__global__ void __launch_bounds__(256) KB_cvt(
    const float* __restrict__ h_in, unsigned int* __restrict__ h8, int n4_h,
    const float* __restrict__ g_in, unsigned int* __restrict__ g8, int n4_g)
{
    const int total = n4_h + n4_g;
    for (int i = blockIdx.x * 256 + threadIdx.x; i < total; i += gridDim.x * 256) {
        const bool isH = (i < n4_h);
        const int  j   = isH ? i : i - n4_h;
        const float4 v = isH ? reinterpret_cast<const float4*>(h_in)[j]
                             : reinterpret_cast<const float4*>(g_in)[j];
        unsigned int w = 0;
        w = __builtin_amdgcn_cvt_pk_fp8_f32(v.x, v.y, w, false);
        w = __builtin_amdgcn_cvt_pk_fp8_f32(v.z, v.w, w, true);
        (isH ? h8 : g8)[j] = w;
    }
}

// ---- main: 8 lanes/edge, 4 edges/group, all gathers in flight ----
__global__ void __launch_bounds__(256, 4) KB_main(
    const unsigned int* __restrict__ h8,   // 32 dwords (128 B) per node row
    const unsigned int* __restrict__ g8,   // 32 dwords per relation row
    const int* __restrict__ eidx,          // [2*E]
    const int* __restrict__ etype,         // [E]
    float* __restrict__ out,               // [E]
    int E)
{
    const int grp = (blockIdx.x * 256 + (int)threadIdx.x) >> 3;  // global group
    const int sub = threadIdx.x & 7;                             // 16 B per lane
    const int e0  = grp * 4;
    if (e0 >= E) return;

    int r[4], c[4], t[4];
    #pragma unroll
    for (int k = 0; k < 4; ++k) {
        const int e = min(e0 + k, E - 1);    // tail clamp (dup compute, store guarded)
        r[k] = eidx[e];
        c[k] = eidx[E + e];
        t[k] = etype[e];
    }

    // Issue ALL 12 row-gathers before consuming anything.
    uint4 hr[4], hc[4], gw[4];
    #pragma unroll
    for (int k = 0; k < 4; ++k)
        hr[k] = *reinterpret_cast<const uint4*>(h8 + (size_t)r[k] * 32 + sub * 4);
    #pragma unroll
    for (int k = 0; k < 4; ++k)
        hc[k] = *reinterpret_cast<const uint4*>(h8 + (size_t)c[k] * 32 + sub * 4);
    #pragma unroll
    for (int k = 0; k < 4; ++k)
        gw[k] = *reinterpret_cast<const uint4*>(g8 + (size_t)t[k] * 32 + sub * 4);

    float s0 = 0.f, s1 = 0.f, s2 = 0.f, s3 = 0.f;
    #pragma unroll
    for (int k = 0; k < 4; ++k) {
        const unsigned int ha[4] = {hr[k].x, hr[k].y, hr[k].z, hr[k].w};
        const unsigned int hb[4] = {hc[k].x, hc[k].y, hc[k].z, hc[k].w};
        const unsigned int gg[4] = {gw[k].x, gw[k].y, gw[k].z, gw[k].w};
        float s = 0.f;
        #pragma unroll
        for (int j = 0; j < 4; ++j) {
            const f32x2 a0 = __builtin_amdgcn_cvt_pk_f32_fp8(ha[j], false);
            const f32x2 a1 = __builtin_amdgcn_cvt_pk_f32_fp8(ha[j], true);
            const f32x2 c0 = __builtin_amdgcn_cvt_pk_f32_fp8(hb[j], false);
            const f32x2 c1 = __builtin_amdgcn_cvt_pk_f32_fp8(hb[j], true);
            const f32x2 g0 = __builtin_amdgcn_cvt_pk_f32_fp8(gg[j], false);
            const f32x2 g1 = __builtin_amdgcn_cvt_pk_f32_fp8(gg[j], true);
            s += fabsf(a0.x + g0.x - c0.x) + fabsf(a0.y + g0.y - c0.y)
               + fabsf(a1.x + g1.x - c1.x) + fabsf(a1.y + g1.y - c1.y);
        }
        // reduce across the 8-lane group (result lands in every lane)
        s += __shfl_xor(s, 4, 8);
        s += __shfl_xor(s, 2, 8);
        s += __shfl_xor(s, 1, 8);
        if (k == 0) s0 = s; else if (k == 1) s1 = s; else if (k == 2) s2 = s; else s3 = s;
    }

    // lanes 0..3 store the group's 4 consecutive outputs (static select, no scratch)
    const float v = (sub == 0) ? s0 : (sub == 1) ? s1 : (sub == 2) ? s2 : s3;
    if (sub < 4 && e0 + sub < E) out[e0 + sub] = v;
}

// ---- fallback: plain f32 path ----
__global__ void __launch_bounds__(256) KB_transe_l1_f32(
    const float* __restrict__ h, const float* __restrict__ g,
    const int* __restrict__ eidx, const int* __restrict__ etype,
    float* __restrict__ out, int E)
{
    const int tid  = blockIdx.x * 256 + threadIdx.x;
    const int edge = tid >> 5;
    const int lane = threadIdx.x & 31;
    if (edge >= E) return;
    const int r = eidx[edge], c = eidx[E + edge], t = etype[edge];
    const int d = lane * 4;
    const float4 hr = *reinterpret_cast<const float4*>(h + (size_t)r * D + d);
    const float4 hc = *reinterpret_cast<const float4*>(h + (size_t)c * D + d);
    const float4 gt = *reinterpret_cast<const float4*>(g + (size_t)t * D + d);
    float s = fabsf(hr.x + gt.x - hc.x) + fabsf(hr.y + gt.y - hc.y)
            + fabsf(hr.z + gt.z - hc.z) + fabsf(hr.w + gt.w - hc.w);
    #pragma unroll
    for (int o = 16; o >= 1; o >>= 1) s += __shfl_xor(s, o, 32);
    if (lane == 0) out[edge] = s;
}

extern "C" void kernel_launch(void* const* d_in, const int* in_sizes, int n_in,
                              void* d_out, int out_size, void* d_ws, size_t ws_size,
                              hipStream_t stream) {
    const float* h     = (const float*)d_in[0];
    const float* g     = (const float*)d_in[1];
    const int*   eidx  = (const int*)d_in[2];
    const int*   etype = (const int*)d_in[3];
    float*       out   = (float*)d_out;

    const int E   = in_sizes[3];
    const int n_h = in_sizes[0];           // 50000*128
    const int n_g = in_sizes[1];           // 500*128

    const size_t need = (size_t)n_h + (size_t)n_g;   // h8 + g8, 1 B/elem
    const bool ok = (n_h % 4 == 0) && (n_g % 4 == 0) && (n_h % D == 0) && (n_g % D == 0);

    if (ws_size >= need && ok) {
        unsigned int* h8 = (unsigned int*)d_ws;
        unsigned int* g8 = (unsigned int*)((char*)d_ws + (size_t)n_h);
        const int n4_h = n_h / 4, n4_g = n_g / 4;
        const int cgrid = (n4_h + n4_g + 255) / 256;
        KB_cvt<<<cgrid, 256, 0, stream>>>(h, h8, n4_h, g, g8, n4_g);

        const int groups = (E + 3) / 4;                   // 4 edges per 8-lane group
        const long long threads = (long long)groups * 8;
        const int grid = (int)((threads + 255) / 256);
        KB_main<<<grid, 256, 0, stream>>>(h8, g8, eidx, etype, out, E);
    } else {
        const long long threads = (long long)E * 32;
        const int grid = (int)((threads + 255) / 256);
        KB_transe_l1_f32<<<grid, 256, 0, stream>>>(h, g, eidx, etype, out, E);
    }
}